// Round 1
// baseline (1258.887 us; speedup 1.0000x reference)
//
#include <hip/hip_runtime.h>

#define NPER 4096
#define MS   1024
#define CIN  64

// Exact d2 matching XLA: per-component sub, square (rounded), left-assoc sum.
// _rn intrinsics prevent fma contraction so borderline in-ball / argmax picks
// match the reference bit-for-bit.
__device__ __forceinline__ float d2_exact(float ax, float ay, float az,
                                          float bx, float by, float bz) {
  float dx = __fsub_rn(ax, bx);
  float dy = __fsub_rn(ay, by);
  float dz = __fsub_rn(az, bz);
  return __fadd_rn(__fadd_rn(__fmul_rn(dx, dx), __fmul_rn(dy, dy)), __fmul_rn(dz, dz));
}

// ---------------- FPS: one block per graph, 512 threads, 8 pts/thread -------
__global__ __launch_bounds__(512) void fps_kernel(const float* __restrict__ pos,
                                                  int* __restrict__ idx_out) {
  const int b = blockIdx.x;
  const int t = threadIdx.x;
  __shared__ float s_pos[NPER * 3];
  __shared__ unsigned long long s_red[8];
  __shared__ int s_next;
  const float* pb = pos + (size_t)b * NPER * 3;
  for (int f = t; f < NPER * 3; f += 512) s_pos[f] = pb[f];
  if (t == 0) idx_out[b * MS] = 0;
  __syncthreads();

  float px[8], py[8], pz[8], dist[8];
#pragma unroll
  for (int j = 0; j < 8; ++j) {
    int i = t + j * 512;
    px[j] = s_pos[i * 3 + 0];
    py[j] = s_pos[i * 3 + 1];
    pz[j] = s_pos[i * 3 + 2];
    dist[j] = __builtin_inff();
  }

  int last = 0;
  for (int m = 1; m < MS; ++m) {
    const float lx = s_pos[last * 3 + 0];
    const float ly = s_pos[last * 3 + 1];
    const float lz = s_pos[last * 3 + 2];
    float bd = -1.0f;
    int bi = 0;
#pragma unroll
    for (int j = 0; j < 8; ++j) {
      float d2 = d2_exact(px[j], py[j], pz[j], lx, ly, lz);
      float nd = fminf(dist[j], d2);
      dist[j] = nd;
      if (nd > bd) { bd = nd; bi = t + j * 512; }  // strict > : first-occurrence tie-break
    }
    // pack: (dist_bits << 32) | ~idx  -> max gives max dist, ties -> min idx (== jnp.argmax)
    unsigned long long key =
        ((unsigned long long)__float_as_uint(bd) << 32) | (unsigned)(~bi);
#pragma unroll
    for (int off = 32; off >= 1; off >>= 1) {
      unsigned hi = __shfl_xor((unsigned)(key >> 32), off, 64);
      unsigned lo = __shfl_xor((unsigned)(key & 0xFFFFFFFFu), off, 64);
      unsigned long long o = ((unsigned long long)hi << 32) | lo;
      if (o > key) key = o;
    }
    if ((t & 63) == 0) s_red[t >> 6] = key;
    __syncthreads();
    if (t == 0) {
      unsigned long long k = s_red[0];
#pragma unroll
      for (int w = 1; w < 8; ++w)
        if (s_red[w] > k) k = s_red[w];
      int nx = (int)(~(unsigned)(k & 0xFFFFFFFFull));
      s_next = nx;
      idx_out[b * MS + m] = nx;
    }
    __syncthreads();
    last = s_next;
  }
}

// ------- radius(top-64-in-ball) + 3-layer MLP + neighbor-max, per query -----
// Block = 256 threads = 4 waves; lane (0..63) = output channel; wave handles
// 16 of the 64 neighbor slots. Weights column-resident in registers (uniform
// LDS broadcast reads for activations).
__global__ __launch_bounds__(256) void radconv_kernel(
    const float* __restrict__ x, const float* __restrict__ pos,
    const int* __restrict__ idx,
    const float* __restrict__ W1, const float* __restrict__ B1,
    const float* __restrict__ W2, const float* __restrict__ B2,
    const float* __restrict__ W3, const float* __restrict__ B3,
    float* __restrict__ out) {
  const int q = blockIdx.x;          // 0..4095
  const int b = q >> 10;             // graph
  const int t = threadIdx.x;
  const float* pb = pos + (size_t)b * NPER * 3;
  const float* xb = x + (size_t)b * NPER * CIN;

  __shared__ float sFeat[64][68];
  __shared__ float sH1[64][68];
  __shared__ unsigned long long s_list[1024];
  __shared__ int s_nbr[64];
  __shared__ int s_cnt;

  if (t == 0) s_cnt = 0;
  __syncthreads();

  const int qi = idx[q];
  const float qx = pb[qi * 3 + 0];
  const float qy = pb[qi * 3 + 1];
  const float qz = pb[qi * 3 + 2];

  // ---- in-ball survivors (threshold 0.04f == f32(0.04), matches JAX's R*R) --
  for (int j0 = 0; j0 < 16; ++j0) {
    int j = t * 16 + j0;
    float d2 = d2_exact(pb[j * 3 + 0], pb[j * 3 + 1], pb[j * 3 + 2], qx, qy, qz);
    if (d2 <= 0.04f) {
      int p = atomicAdd(&s_cnt, 1);
      if (p < 1024)
        s_list[p] = ((unsigned long long)__float_as_uint(d2) << 32) | (unsigned)j;
    }
  }
  __syncthreads();
  const int nsurv = min(s_cnt, 1024);
  const int cnt = min(nsurv, 64);

  // ---- exact top-64 by (d2, idx) via rank (keys are unique) ----------------
  for (int e = t; e < nsurv; e += 256) {
    unsigned long long mykey = s_list[e];
    int rank = 0;
    for (int o = 0; o < nsurv; ++o) rank += (s_list[o] < mykey) ? 1 : 0;
    if (rank < 64) s_nbr[rank] = (int)(mykey & 0xFFFFFFFFull);
  }
  __syncthreads();

  // ---- gather feat = [x_j (64) | pos_j - pos_i (3) | 0 pad] ----------------
  {
    const int s = t >> 2, r = t & 3;
    float4* fw = (float4*)(&sFeat[s][r * 16]);
    if (s < cnt) {
      const int j = s_nbr[s];
      const float4* xr = (const float4*)(xb + (size_t)j * CIN + r * 16);
      fw[0] = xr[0]; fw[1] = xr[1]; fw[2] = xr[2]; fw[3] = xr[3];
      if (r == 0) {
        sFeat[s][64] = pb[j * 3 + 0] - qx;
        sFeat[s][65] = pb[j * 3 + 1] - qy;
        sFeat[s][66] = pb[j * 3 + 2] - qz;
        sFeat[s][67] = 0.f;
      }
    } else {
      float4 z = make_float4(0.f, 0.f, 0.f, 0.f);
      fw[0] = z; fw[1] = z; fw[2] = z; fw[3] = z;
      if (r == 0) {
        sFeat[s][64] = 0.f; sFeat[s][65] = 0.f; sFeat[s][66] = 0.f; sFeat[s][67] = 0.f;
      }
    }
  }

  const int l = t & 63, w = t >> 6;

  // ---- layer 1: 67 -> 64 ---------------------------------------------------
  float w1r[68];
#pragma unroll
  for (int k = 0; k < 67; ++k) w1r[k] = W1[k * 64 + l];
  w1r[67] = 0.f;
  const float bb1 = B1[l];
  __syncthreads();  // covers gather too

  for (int n0 = 0; n0 < 16; ++n0) {
    const int nn = w * 16 + n0;
    float acc = bb1;
    const float4* f4 = (const float4*)(&sFeat[nn][0]);
#pragma unroll
    for (int k4 = 0; k4 < 17; ++k4) {
      float4 f = f4[k4];
      acc = fmaf(f.x, w1r[k4 * 4 + 0], acc);
      acc = fmaf(f.y, w1r[k4 * 4 + 1], acc);
      acc = fmaf(f.z, w1r[k4 * 4 + 2], acc);
      acc = fmaf(f.w, w1r[k4 * 4 + 3], acc);
    }
    sH1[nn][l] = fmaxf(acc, 0.f);
  }
  __syncthreads();

  // ---- layer 2: 64 -> 64 ---------------------------------------------------
  float w2r[64];
#pragma unroll
  for (int k = 0; k < 64; ++k) w2r[k] = W2[k * 64 + l];
  const float bb2 = B2[l];
  for (int n0 = 0; n0 < 16; ++n0) {
    const int nn = w * 16 + n0;
    float acc = bb2;
    const float4* f4 = (const float4*)(&sH1[nn][0]);
#pragma unroll
    for (int k4 = 0; k4 < 16; ++k4) {
      float4 f = f4[k4];
      acc = fmaf(f.x, w2r[k4 * 4 + 0], acc);
      acc = fmaf(f.y, w2r[k4 * 4 + 1], acc);
      acc = fmaf(f.z, w2r[k4 * 4 + 2], acc);
      acc = fmaf(f.w, w2r[k4 * 4 + 3], acc);
    }
    sFeat[nn][l] = fmaxf(acc, 0.f);  // h2 overwrites feat
  }
  __syncthreads();

  // ---- layer 3: 64 -> 128, fused neighbor-max ------------------------------
  float w3a[64], w3b[64];
#pragma unroll
  for (int k = 0; k < 64; ++k) {
    w3a[k] = W3[k * 128 + l];
    w3b[k] = W3[k * 128 + 64 + l];
  }
  const float bb3a = B3[l], bb3b = B3[64 + l];
  float m0 = -3.0e38f, m1 = -3.0e38f;
  for (int n0 = 0; n0 < 16; ++n0) {
    const int nn = w * 16 + n0;
    if (nn < cnt) {  // uniform per wave; invalid slots masked like ref's -inf
      float a0 = bb3a, a1 = bb3b;
      const float4* f4 = (const float4*)(&sFeat[nn][0]);
#pragma unroll
      for (int k4 = 0; k4 < 16; ++k4) {
        float4 f = f4[k4];
        a0 = fmaf(f.x, w3a[k4 * 4 + 0], a0); a1 = fmaf(f.x, w3b[k4 * 4 + 0], a1);
        a0 = fmaf(f.y, w3a[k4 * 4 + 1], a0); a1 = fmaf(f.y, w3b[k4 * 4 + 1], a1);
        a0 = fmaf(f.z, w3a[k4 * 4 + 2], a0); a1 = fmaf(f.z, w3b[k4 * 4 + 2], a1);
        a0 = fmaf(f.w, w3a[k4 * 4 + 3], a0); a1 = fmaf(f.w, w3b[k4 * 4 + 3], a1);
      }
      m0 = fmaxf(m0, fmaxf(a0, 0.f));
      m1 = fmaxf(m1, fmaxf(a1, 0.f));
    }
  }
  float* red = &sH1[0][0];  // sH1 dead after layer2 barrier
  red[w * 128 + l] = m0;
  red[w * 128 + 64 + l] = m1;
  __syncthreads();
  if (t < 128) {
    float v = fmaxf(fmaxf(red[t], red[128 + t]), fmaxf(red[256 + t], red[384 + t]));
    out[(size_t)q * 128 + t] = v;
  }
  if (t == 128) {
    out[524288 + q * 3 + 0] = qx;
    out[524288 + q * 3 + 1] = qy;
    out[524288 + q * 3 + 2] = qz;
    out[536576 + q] = (float)b;  // batch_s as f32 value
  }
}

extern "C" void kernel_launch(void* const* d_in, const int* in_sizes, int n_in,
                              void* d_out, int out_size, void* d_ws, size_t ws_size,
                              hipStream_t stream) {
  const float* x   = (const float*)d_in[0];
  const float* pos = (const float*)d_in[1];
  const float* W1  = (const float*)d_in[3];
  const float* B1  = (const float*)d_in[4];
  const float* W2  = (const float*)d_in[5];
  const float* B2  = (const float*)d_in[6];
  const float* W3  = (const float*)d_in[7];
  const float* B3  = (const float*)d_in[8];
  float* out = (float*)d_out;
  int* idx = (int*)d_ws;  // 4096 ints

  fps_kernel<<<4, 512, 0, stream>>>(pos, idx);
  radconv_kernel<<<4096, 256, 0, stream>>>(x, pos, idx, W1, B1, W2, B2, W3, B3, out);
}

// Round 2
// 1018.728 us; speedup vs baseline: 1.2357x; 1.2357x over previous
//
#include <hip/hip_runtime.h>

#define NPER 4096
#define MS   1024
#define CIN  64

// Exact d2 matching the numpy/XLA reference: per-component sub, rounded square,
// left-assoc sum. _rn intrinsics forbid fma contraction so borderline in-ball /
// argmax picks match bit-for-bit (R1: absmax == 0.0).
__device__ __forceinline__ float d2_exact(float ax, float ay, float az,
                                          float bx, float by, float bz) {
  float dx = __fsub_rn(ax, bx);
  float dy = __fsub_rn(ay, by);
  float dz = __fsub_rn(az, bz);
  return __fadd_rn(__fadd_rn(__fmul_rn(dx, dx), __fmul_rn(dy, dy)), __fmul_rn(dz, dz));
}

// One DPP max-combine step on a packed u64 key (VALU pipe, no LDS latency).
// Invalid/masked lanes keep `old` (= current k) so the max is a no-op there.
template <int CTRL, int RMASK>
__device__ __forceinline__ unsigned long long dpp_max_step(unsigned long long k) {
  int hi = (int)(unsigned)(k >> 32);
  int lo = (int)(unsigned)(k & 0xFFFFFFFFull);
  int thi = __builtin_amdgcn_update_dpp(hi, hi, CTRL, RMASK, 0xF, false);
  int tlo = __builtin_amdgcn_update_dpp(lo, lo, CTRL, RMASK, 0xF, false);
  unsigned long long t =
      ((unsigned long long)(unsigned)thi << 32) | (unsigned)tlo;
  return t > k ? t : k;
}

// ---------------- FPS: one block per graph, 256 threads, 16 pts/thread ------
// Per iter: register d2+min+best (issue-bound ~384cy) -> in-wave DPP butterfly
// (row_shr 1/2/4/8 + row_bcast15/31, lane63 holds wave max) -> lane63 writes
// key -> ONE barrier -> all threads redundantly reduce the 4 wave keys
// (broadcast b128 reads) -> winner coords via one b128 read. s_red is
// parity-double-buffered so no second barrier is needed.
__global__ __launch_bounds__(256) void fps_kernel(const float* __restrict__ pos,
                                                  int* __restrict__ idx_out) {
  const int b = blockIdx.x;
  const int t = threadIdx.x;
  __shared__ float4 s_pos4[NPER];                       // 64 KB
  __shared__ __align__(16) unsigned long long s_red[2][4];
  const float* pb = pos + (size_t)b * NPER * 3;
  for (int i = t; i < NPER; i += 256)
    s_pos4[i] = make_float4(pb[i * 3], pb[i * 3 + 1], pb[i * 3 + 2], 0.f);
  if (t == 0) idx_out[b * MS] = 0;
  __syncthreads();

  float px[16], py[16], pz[16], dist[16];
#pragma unroll
  for (int j = 0; j < 16; ++j) {
    float4 p = s_pos4[t + j * 256];
    px[j] = p.x; py[j] = p.y; pz[j] = p.z;
    dist[j] = __builtin_inff();
  }
  const int w = t >> 6;
  const int lane = t & 63;

  float lx = s_pos4[0].x, ly = s_pos4[0].y, lz = s_pos4[0].z;

  for (int m = 1; m < MS; ++m) {
    float bd = -1.0f;
    int bi = 0;
#pragma unroll
    for (int j = 0; j < 16; ++j) {
      float d2 = d2_exact(px[j], py[j], pz[j], lx, ly, lz);
      float nd = fminf(dist[j], d2);
      dist[j] = nd;
      if (nd > bd) { bd = nd; bi = t + j * 256; }  // strict >: lowest idx on tie
    }
    // pack (dist_bits << 32) | ~idx : u64 max == max dist, tie -> min idx
    unsigned long long k =
        ((unsigned long long)__float_as_uint(bd) << 32) | (unsigned)(~bi);
    k = dpp_max_step<0x111, 0xF>(k);  // row_shr:1
    k = dpp_max_step<0x112, 0xF>(k);  // row_shr:2
    k = dpp_max_step<0x114, 0xF>(k);  // row_shr:4
    k = dpp_max_step<0x118, 0xF>(k);  // row_shr:8  -> lane15 of each row = row max
    k = dpp_max_step<0x142, 0xA>(k);  // row_bcast15 -> lane31=max(0..31), lane63=max(32..63)
    k = dpp_max_step<0x143, 0xC>(k);  // row_bcast31 -> lane63 = max(0..63)
    const int par = m & 1;
    if (lane == 63) s_red[par][w] = k;
    __syncthreads();
    ulonglong2 ab = *reinterpret_cast<const ulonglong2*>(&s_red[par][0]);
    ulonglong2 cd = *reinterpret_cast<const ulonglong2*>(&s_red[par][2]);
    unsigned long long kb = ab.x;
    if (ab.y > kb) kb = ab.y;
    if (cd.x > kb) kb = cd.x;
    if (cd.y > kb) kb = cd.y;
    const int nx = (int)(~(unsigned)(kb & 0xFFFFFFFFull));
    if (t == 0) idx_out[b * MS + m] = nx;
    float4 wp = s_pos4[nx];   // broadcast read
    lx = wp.x; ly = wp.y; lz = wp.z;
  }
}

// ------- radius(top-64-in-ball) + 3-layer MLP + neighbor-max, per query -----
__global__ __launch_bounds__(256) void radconv_kernel(
    const float* __restrict__ x, const float* __restrict__ pos,
    const int* __restrict__ idx,
    const float* __restrict__ W1, const float* __restrict__ B1,
    const float* __restrict__ W2, const float* __restrict__ B2,
    const float* __restrict__ W3, const float* __restrict__ B3,
    float* __restrict__ out) {
  const int q = blockIdx.x;          // 0..4095
  const int b = q >> 10;             // graph
  const int t = threadIdx.x;
  const float* pb = pos + (size_t)b * NPER * 3;
  const float* xb = x + (size_t)b * NPER * CIN;

  __shared__ float sFeat[64][68];
  __shared__ float sH1[64][68];
  __shared__ unsigned long long s_list[512];   // max in-ball count ~210 << 512
  __shared__ int s_nbr[64];
  __shared__ int s_cnt;

  if (t == 0) s_cnt = 0;
  __syncthreads();

  const int qi = idx[q];
  const float qx = pb[qi * 3 + 0];
  const float qy = pb[qi * 3 + 1];
  const float qz = pb[qi * 3 + 2];

  // ---- in-ball survivors; 16 pts/thread via 12 float4 loads ----------------
  {
    float pp[48];
    const float4* pv = (const float4*)(pb + (size_t)t * 48);
#pragma unroll
    for (int r = 0; r < 12; ++r) {
      float4 v = pv[r];
      pp[r * 4 + 0] = v.x; pp[r * 4 + 1] = v.y;
      pp[r * 4 + 2] = v.z; pp[r * 4 + 3] = v.w;
    }
#pragma unroll
    for (int j0 = 0; j0 < 16; ++j0) {
      int j = t * 16 + j0;
      float d2 = d2_exact(pp[j0 * 3], pp[j0 * 3 + 1], pp[j0 * 3 + 2], qx, qy, qz);
      if (d2 <= 0.04f) {  // f32(0.04) == JAX's R*R
        int p = atomicAdd(&s_cnt, 1);
        if (p < 512)
          s_list[p] = ((unsigned long long)__float_as_uint(d2) << 32) | (unsigned)j;
      }
    }
  }
  __syncthreads();
  const int nsurv = min(s_cnt, 512);
  const int cnt = min(nsurv, 64);

  // ---- exact top-64 by (d2, idx) via rank; 8-batched broadcast reads -------
  for (int e = t; e < nsurv; e += 256) {
    unsigned long long mykey = s_list[e];
    int rank = 0;
    int o = 0;
    for (; o + 8 <= nsurv; o += 8) {
      unsigned long long k0 = s_list[o + 0], k1 = s_list[o + 1];
      unsigned long long k2 = s_list[o + 2], k3 = s_list[o + 3];
      unsigned long long k4 = s_list[o + 4], k5 = s_list[o + 5];
      unsigned long long k6 = s_list[o + 6], k7 = s_list[o + 7];
      rank += (k0 < mykey) + (k1 < mykey) + (k2 < mykey) + (k3 < mykey) +
              (k4 < mykey) + (k5 < mykey) + (k6 < mykey) + (k7 < mykey);
    }
    for (; o < nsurv; ++o) rank += (s_list[o] < mykey) ? 1 : 0;
    if (rank < 64) s_nbr[rank] = (int)(mykey & 0xFFFFFFFFull);
  }
  __syncthreads();

  // ---- gather feat = [x_j (64) | pos_j - pos_i (3) | 0 pad] ----------------
  {
    const int s = t >> 2, r = t & 3;
    float4* fw = (float4*)(&sFeat[s][r * 16]);
    if (s < cnt) {
      const int j = s_nbr[s];
      const float4* xr = (const float4*)(xb + (size_t)j * CIN + r * 16);
      fw[0] = xr[0]; fw[1] = xr[1]; fw[2] = xr[2]; fw[3] = xr[3];
      if (r == 0) {
        sFeat[s][64] = pb[j * 3 + 0] - qx;
        sFeat[s][65] = pb[j * 3 + 1] - qy;
        sFeat[s][66] = pb[j * 3 + 2] - qz;
        sFeat[s][67] = 0.f;
      }
    } else {
      float4 z = make_float4(0.f, 0.f, 0.f, 0.f);
      fw[0] = z; fw[1] = z; fw[2] = z; fw[3] = z;
      if (r == 0) {
        sFeat[s][64] = 0.f; sFeat[s][65] = 0.f; sFeat[s][66] = 0.f; sFeat[s][67] = 0.f;
      }
    }
  }

  const int l = t & 63, w = t >> 6;

  // ---- layer 1: 67 -> 64 ---------------------------------------------------
  float w1r[68];
#pragma unroll
  for (int k = 0; k < 67; ++k) w1r[k] = W1[k * 64 + l];
  w1r[67] = 0.f;
  const float bb1 = B1[l];
  __syncthreads();  // covers gather too

#pragma unroll 2
  for (int n0 = 0; n0 < 16; ++n0) {
    const int nn = w * 16 + n0;
    float acc = bb1;
    const float4* f4 = (const float4*)(&sFeat[nn][0]);
#pragma unroll
    for (int k4 = 0; k4 < 17; ++k4) {
      float4 f = f4[k4];
      acc = fmaf(f.x, w1r[k4 * 4 + 0], acc);
      acc = fmaf(f.y, w1r[k4 * 4 + 1], acc);
      acc = fmaf(f.z, w1r[k4 * 4 + 2], acc);
      acc = fmaf(f.w, w1r[k4 * 4 + 3], acc);
    }
    sH1[nn][l] = fmaxf(acc, 0.f);
  }
  __syncthreads();

  // ---- layer 2: 64 -> 64 ---------------------------------------------------
  float w2r[64];
#pragma unroll
  for (int k = 0; k < 64; ++k) w2r[k] = W2[k * 64 + l];
  const float bb2 = B2[l];
#pragma unroll 2
  for (int n0 = 0; n0 < 16; ++n0) {
    const int nn = w * 16 + n0;
    float acc = bb2;
    const float4* f4 = (const float4*)(&sH1[nn][0]);
#pragma unroll
    for (int k4 = 0; k4 < 16; ++k4) {
      float4 f = f4[k4];
      acc = fmaf(f.x, w2r[k4 * 4 + 0], acc);
      acc = fmaf(f.y, w2r[k4 * 4 + 1], acc);
      acc = fmaf(f.z, w2r[k4 * 4 + 2], acc);
      acc = fmaf(f.w, w2r[k4 * 4 + 3], acc);
    }
    sFeat[nn][l] = fmaxf(acc, 0.f);  // h2 overwrites feat
  }
  __syncthreads();

  // ---- layer 3: 64 -> 128, fused neighbor-max ------------------------------
  float w3a[64], w3b[64];
#pragma unroll
  for (int k = 0; k < 64; ++k) {
    w3a[k] = W3[k * 128 + l];
    w3b[k] = W3[k * 128 + 64 + l];
  }
  const float bb3a = B3[l], bb3b = B3[64 + l];
  float m0 = -3.0e38f, m1 = -3.0e38f;
#pragma unroll 2
  for (int n0 = 0; n0 < 16; ++n0) {
    const int nn = w * 16 + n0;
    if (nn < cnt) {  // uniform per wave
      float a0 = bb3a, a1 = bb3b;
      const float4* f4 = (const float4*)(&sFeat[nn][0]);
#pragma unroll
      for (int k4 = 0; k4 < 16; ++k4) {
        float4 f = f4[k4];
        a0 = fmaf(f.x, w3a[k4 * 4 + 0], a0); a1 = fmaf(f.x, w3b[k4 * 4 + 0], a1);
        a0 = fmaf(f.y, w3a[k4 * 4 + 1], a0); a1 = fmaf(f.y, w3b[k4 * 4 + 1], a1);
        a0 = fmaf(f.z, w3a[k4 * 4 + 2], a0); a1 = fmaf(f.z, w3b[k4 * 4 + 2], a1);
        a0 = fmaf(f.w, w3a[k4 * 4 + 3], a0); a1 = fmaf(f.w, w3b[k4 * 4 + 3], a1);
      }
      m0 = fmaxf(m0, fmaxf(a0, 0.f));
      m1 = fmaxf(m1, fmaxf(a1, 0.f));
    }
  }
  float* red = &sH1[0][0];  // sH1 dead after layer2 barrier
  red[w * 128 + l] = m0;
  red[w * 128 + 64 + l] = m1;
  __syncthreads();
  if (t < 128) {
    float v = fmaxf(fmaxf(red[t], red[128 + t]), fmaxf(red[256 + t], red[384 + t]));
    out[(size_t)q * 128 + t] = v;
  }
  if (t == 128) {
    out[524288 + q * 3 + 0] = qx;
    out[524288 + q * 3 + 1] = qy;
    out[524288 + q * 3 + 2] = qz;
    out[536576 + q] = (float)b;  // batch_s as f32 value
  }
}

extern "C" void kernel_launch(void* const* d_in, const int* in_sizes, int n_in,
                              void* d_out, int out_size, void* d_ws, size_t ws_size,
                              hipStream_t stream) {
  const float* x   = (const float*)d_in[0];
  const float* pos = (const float*)d_in[1];
  const float* W1  = (const float*)d_in[3];
  const float* B1  = (const float*)d_in[4];
  const float* W2  = (const float*)d_in[5];
  const float* B2  = (const float*)d_in[6];
  const float* W3  = (const float*)d_in[7];
  const float* B3  = (const float*)d_in[8];
  float* out = (float*)d_out;
  int* idx = (int*)d_ws;  // 4096 ints

  fps_kernel<<<4, 256, 0, stream>>>(pos, idx);
  radconv_kernel<<<4096, 256, 0, stream>>>(x, pos, idx, W1, B1, W2, B2, W3, B3, out);
}

// Round 3
// 697.707 us; speedup vs baseline: 1.8043x; 1.4601x over previous
//
#include <hip/hip_runtime.h>

#define NPER 4096
#define MS   1024
#define CIN  64
#define LCAP 384

typedef float  f32x4 __attribute__((ext_vector_type(4)));
typedef short  s16x8 __attribute__((ext_vector_type(8)));

// Exact d2 matching the numpy/XLA reference: per-component sub, rounded square,
// left-assoc sum. _rn forbids fma contraction -> bit-exact ball/argmax decisions.
__device__ __forceinline__ float d2_exact(float ax, float ay, float az,
                                          float bx, float by, float bz) {
  float dx = __fsub_rn(ax, bx);
  float dy = __fsub_rn(ay, by);
  float dz = __fsub_rn(az, bz);
  return __fadd_rn(__fadd_rn(__fmul_rn(dx, dx), __fmul_rn(dy, dy)), __fmul_rn(dz, dz));
}

// f32 -> bf16 (RNE) bit pattern
__device__ __forceinline__ unsigned short f2bf(float f) {
  unsigned b = __float_as_uint(f);
  return (unsigned short)((b + 0x7FFFu + ((b >> 16) & 1u)) >> 16);
}

template <int CTRL, int RMASK>
__device__ __forceinline__ unsigned long long dpp_max_step(unsigned long long k) {
  int hi = (int)(unsigned)(k >> 32);
  int lo = (int)(unsigned)(k & 0xFFFFFFFFull);
  int thi = __builtin_amdgcn_update_dpp(hi, hi, CTRL, RMASK, 0xF, false);
  int tlo = __builtin_amdgcn_update_dpp(lo, lo, CTRL, RMASK, 0xF, false);
  unsigned long long t =
      ((unsigned long long)(unsigned)thi << 32) | (unsigned)tlo;
  return t > k ? t : k;
}

__device__ __forceinline__ unsigned long long u64max(unsigned long long a,
                                                    unsigned long long b) {
  return a > b ? a : b;
}

// ---------------- FPS: one block per graph, 512 threads, 8 pts/thread ------
// Per iter: register d2+min+best -> DPP butterfly (lane63 = wave max) ->
// lane63 writes key -> ONE barrier -> all threads reduce 8 wave keys via
// 4x b128 broadcast reads + tree -> winner coords via one b128 read.
// s_red parity-double-buffered (no second barrier).
__global__ __launch_bounds__(512) void fps_kernel(const float* __restrict__ pos,
                                                  int* __restrict__ idx_out) {
  const int b = blockIdx.x;
  const int t = threadIdx.x;
  __shared__ float4 s_pos4[NPER];                       // 64 KB
  __shared__ __align__(16) unsigned long long s_red[2][8];
  const float* pb = pos + (size_t)b * NPER * 3;
  for (int i = t; i < NPER; i += 512)
    s_pos4[i] = make_float4(pb[i * 3], pb[i * 3 + 1], pb[i * 3 + 2], 0.f);
  if (t == 0) idx_out[b * MS] = 0;
  __syncthreads();

  float px[8], py[8], pz[8], dist[8];
#pragma unroll
  for (int j = 0; j < 8; ++j) {
    float4 p = s_pos4[t + j * 512];
    px[j] = p.x; py[j] = p.y; pz[j] = p.z;
    dist[j] = __builtin_inff();
  }
  const int w = t >> 6;
  const int lane = t & 63;

  float lx = s_pos4[0].x, ly = s_pos4[0].y, lz = s_pos4[0].z;

  for (int m = 1; m < MS; ++m) {
    float bd = -1.0f;
    int bi = 0;
#pragma unroll
    for (int j = 0; j < 8; ++j) {
      float d2 = d2_exact(px[j], py[j], pz[j], lx, ly, lz);
      float nd = fminf(dist[j], d2);
      dist[j] = nd;
      if (nd > bd) { bd = nd; bi = t + j * 512; }  // strict >: lowest idx on tie
    }
    unsigned long long k =
        ((unsigned long long)__float_as_uint(bd) << 32) | (unsigned)(~bi);
    k = dpp_max_step<0x111, 0xF>(k);  // row_shr:1
    k = dpp_max_step<0x112, 0xF>(k);  // row_shr:2
    k = dpp_max_step<0x114, 0xF>(k);  // row_shr:4
    k = dpp_max_step<0x118, 0xF>(k);  // row_shr:8
    k = dpp_max_step<0x142, 0xA>(k);  // row_bcast15
    k = dpp_max_step<0x143, 0xC>(k);  // row_bcast31 -> lane63 = wave max
    const int par = m & 1;
    if (lane == 63) s_red[par][w] = k;
    __syncthreads();
    ulonglong2 p0 = *reinterpret_cast<const ulonglong2*>(&s_red[par][0]);
    ulonglong2 p1 = *reinterpret_cast<const ulonglong2*>(&s_red[par][2]);
    ulonglong2 p2 = *reinterpret_cast<const ulonglong2*>(&s_red[par][4]);
    ulonglong2 p3 = *reinterpret_cast<const ulonglong2*>(&s_red[par][6]);
    unsigned long long a = u64max(p0.x, p0.y);
    unsigned long long c = u64max(p1.x, p1.y);
    unsigned long long d = u64max(p2.x, p2.y);
    unsigned long long e = u64max(p3.x, p3.y);
    unsigned long long kb = u64max(u64max(a, c), u64max(d, e));
    const int nx = (int)(~(unsigned)(kb & 0xFFFFFFFFull));
    if (t == 0) idx_out[b * MS + m] = nx;
    float4 wp = s_pos4[nx];  // broadcast read
    lx = wp.x; ly = wp.y; lz = wp.z;
  }
}

// ---- radius(top-64) + MFMA-bf16 MLP + masked neighbor max -----------------
// 2 queries/block, 512 threads (8 waves; 4 waves/query, wave owns 16 rows).
// LDS row strides are ODD multiples of 16B (208B/144B) -> ds_read_b128 frags
// are ~2-way bank conflicts (free). h overwrites feat cols 0..63 per layer;
// each wave rewrites only its own 16-row stripe -> no barrier inside the MLP.
__global__ __launch_bounds__(512, 4) void radconv_kernel(
    const float* __restrict__ x, const float* __restrict__ pos,
    const int* __restrict__ idx,
    const float* __restrict__ W1, const float* __restrict__ B1,
    const float* __restrict__ W2, const float* __restrict__ B2,
    const float* __restrict__ W3, const float* __restrict__ B3,
    float* __restrict__ out) {
  const int t = threadIdx.x;
  const int g = blockIdx.x >> 9;          // graph
  const int qpair = blockIdx.x & 511;     // 512 blocks/graph * 2 queries
  const float* pb = pos + (size_t)g * NPER * 3;
  const float* xb = x + (size_t)g * NPER * CIN;

  __shared__ int s_cnt[2];
  __shared__ float s_ctr[2][4];
  __shared__ __align__(16) unsigned long long s_list[2][LCAP];  // 6 KB
  __shared__ int s_nbr[2][64];
  __shared__ __align__(16) unsigned short sFeat[2][64 * 104];   // 26 KB (reused as red)
  __shared__ __align__(16) unsigned short sW1[64 * 104];        // 13 KB  [col][k<=96pad]
  __shared__ __align__(16) unsigned short sW2[64 * 72];         // 9 KB   [col][k=64+pad]
  __shared__ __align__(16) unsigned short sW3[128 * 72];        // 18 KB

  if (t < 2) s_cnt[t] = 0;
  const int q0 = g * MS + qpair * 2;
  const int qiA = idx[q0], qiB = idx[q0 + 1];
  const float cAx = pb[qiA * 3], cAy = pb[qiA * 3 + 1], cAz = pb[qiA * 3 + 2];
  const float cBx = pb[qiB * 3], cBy = pb[qiB * 3 + 1], cBz = pb[qiB * 3 + 2];
  if (t == 0) { s_ctr[0][0] = cAx; s_ctr[0][1] = cAy; s_ctr[0][2] = cAz; }
  if (t == 1) { s_ctr[1][0] = cBx; s_ctr[1][1] = cBy; s_ctr[1][2] = cBz; }
  __syncthreads();  // B1: s_cnt zeroed

  // ---- search: 8 pts/thread, both queries --------------------------------
  {
    float pp[24];
    const float4* pv = (const float4*)(pb + (size_t)t * 24);
#pragma unroll
    for (int r = 0; r < 6; ++r) {
      float4 v = pv[r];
      pp[r * 4 + 0] = v.x; pp[r * 4 + 1] = v.y;
      pp[r * 4 + 2] = v.z; pp[r * 4 + 3] = v.w;
    }
#pragma unroll
    for (int jj = 0; jj < 8; ++jj) {
      const int j = t * 8 + jj;
      const float X = pp[jj * 3], Y = pp[jj * 3 + 1], Z = pp[jj * 3 + 2];
      float dA = d2_exact(X, Y, Z, cAx, cAy, cAz);
      if (dA <= 0.04f) {  // f32(0.04) == JAX's R*R
        int p = atomicAdd(&s_cnt[0], 1);
        if (p < LCAP)
          s_list[0][p] = ((unsigned long long)__float_as_uint(dA) << 32) | (unsigned)j;
      }
      float dB = d2_exact(X, Y, Z, cBx, cBy, cBz);
      if (dB <= 0.04f) {
        int p = atomicAdd(&s_cnt[1], 1);
        if (p < LCAP)
          s_list[1][p] = ((unsigned long long)__float_as_uint(dB) << 32) | (unsigned)j;
      }
    }
  }
  // ---- stage weights (bf16, transposed) — independent of search ----------
  for (int ee = t; ee < 64 * 64; ee += 512) {           // zero W1 k-pad 67..103
    int c = ee >> 6, kk = 67 + (ee & 63);
    if (kk < 104) sW1[c * 104 + kk] = 0;
  }
  for (int e = t; e < 67 * 64; e += 512) {              // W1t[c][k] = W1[k][c]
    int k = e >> 6, c = e & 63;
    sW1[c * 104 + k] = f2bf(W1[e]);
  }
  for (int e = t; e < 64 * 64; e += 512) {
    int k = e >> 6, c = e & 63;
    sW2[c * 72 + k] = f2bf(W2[e]);
  }
  for (int e = t; e < 64 * 128; e += 512) {
    int k = e >> 7, c = e & 127;
    sW3[c * 72 + k] = f2bf(W3[e]);
  }
  __syncthreads();  // B2: lists + weights ready

  const int w = t >> 6, lane = t & 63;
  const int c0 = min(min(s_cnt[0], LCAP), 64);
  const int c1 = min(min(s_cnt[1], LCAP), 64);

  // ---- exact top-64 by (d2, idx) via rank; 4 waves per query -------------
  {
    const int rq = w >> 2;
    const int nsurv = min(s_cnt[rq], LCAP);
    for (int e = (w & 3) * 64 + lane; e < nsurv; e += 256) {
      unsigned long long mykey = s_list[rq][e];
      int rank = 0;
      int o = 0;
      for (; o + 8 <= nsurv; o += 8) {
        unsigned long long k0 = s_list[rq][o + 0], k1 = s_list[rq][o + 1];
        unsigned long long k2 = s_list[rq][o + 2], k3 = s_list[rq][o + 3];
        unsigned long long k4 = s_list[rq][o + 4], k5 = s_list[rq][o + 5];
        unsigned long long k6 = s_list[rq][o + 6], k7 = s_list[rq][o + 7];
        rank += (k0 < mykey) + (k1 < mykey) + (k2 < mykey) + (k3 < mykey) +
                (k4 < mykey) + (k5 < mykey) + (k6 < mykey) + (k7 < mykey);
      }
      for (; o < nsurv; ++o) rank += (s_list[rq][o] < mykey) ? 1 : 0;
      if (rank < 64) s_nbr[rq][rank] = (int)(mykey & 0xFFFFFFFFull);
    }
  }
  __syncthreads();  // B3: nbr lists ready

  // ---- gather feat rows: [x_j bf16 (64) | rel (3) | 0 pad ... 96) --------
  {
    const int slot = t >> 2, part = t & 3;   // 128 slots x 4 parts
    const int gq = slot >> 6, s = slot & 63;
    const int cq = gq ? c1 : c0;
    unsigned short* frow = &sFeat[gq][s * 104];
    uint4 z; z.x = z.y = z.z = z.w = 0u;
    if (s < cq) {
      const int j = s_nbr[gq][s];
      const float4* xr = (const float4*)(xb + (size_t)j * CIN + part * 16);
      float4 v0 = xr[0], v1 = xr[1], v2 = xr[2], v3 = xr[3];
      uint4 w0, w1;
      w0.x = f2bf(v0.x) | ((unsigned)f2bf(v0.y) << 16);
      w0.y = f2bf(v0.z) | ((unsigned)f2bf(v0.w) << 16);
      w0.z = f2bf(v1.x) | ((unsigned)f2bf(v1.y) << 16);
      w0.w = f2bf(v1.z) | ((unsigned)f2bf(v1.w) << 16);
      w1.x = f2bf(v2.x) | ((unsigned)f2bf(v2.y) << 16);
      w1.y = f2bf(v2.z) | ((unsigned)f2bf(v2.w) << 16);
      w1.z = f2bf(v3.x) | ((unsigned)f2bf(v3.y) << 16);
      w1.w = f2bf(v3.z) | ((unsigned)f2bf(v3.w) << 16);
      *(uint4*)(frow + part * 16) = w0;
      *(uint4*)(frow + part * 16 + 8) = w1;
      uint4 rz = z;
      if (part == 0) {
        const float cx = gq ? cBx : cAx, cy = gq ? cBy : cAy, cz = gq ? cBz : cAz;
        rz.x = f2bf(pb[j * 3] - cx) | ((unsigned)f2bf(pb[j * 3 + 1] - cy) << 16);
        rz.y = (unsigned)f2bf(pb[j * 3 + 2] - cz);
      }
      *(uint4*)(frow + 64 + part * 8) = rz;
    } else {
      *(uint4*)(frow + part * 16) = z;
      *(uint4*)(frow + part * 16 + 8) = z;
      *(uint4*)(frow + 64 + part * 8) = z;
    }
  }
  __syncthreads();  // B4: feat ready

  // ---- MFMA MLP: wave -> (query qq2, row tile mt) ------------------------
  const int qq2 = w >> 2;
  const int mt = w & 3;
  const int lo = lane & 15, hi = lane >> 4;
  unsigned short* F = &sFeat[qq2][0];
  const int arow = (16 * mt + lo) * 104;
  const int hrow = (16 * mt + hi * 4) * 104;

  // layer 1: K=96 (3 steps), N=64 (4 tiles)
  {
    f32x4 acc[4];
#pragma unroll
    for (int n = 0; n < 4; ++n) {
      float bb = B1[n * 16 + lo];
      acc[n] = (f32x4){bb, bb, bb, bb};
    }
    s16x8 a0 = *(const s16x8*)(F + arow + 0 + hi * 8);
    s16x8 a1 = *(const s16x8*)(F + arow + 32 + hi * 8);
    s16x8 a2 = *(const s16x8*)(F + arow + 64 + hi * 8);
#pragma unroll
    for (int n = 0; n < 4; ++n) {
      const unsigned short* Bp = &sW1[(n * 16 + lo) * 104 + hi * 8];
      s16x8 b0 = *(const s16x8*)(Bp);
      s16x8 b1 = *(const s16x8*)(Bp + 32);
      s16x8 b2 = *(const s16x8*)(Bp + 64);
      acc[n] = __builtin_amdgcn_mfma_f32_16x16x32_bf16(a0, b0, acc[n], 0, 0, 0);
      acc[n] = __builtin_amdgcn_mfma_f32_16x16x32_bf16(a1, b1, acc[n], 0, 0, 0);
      acc[n] = __builtin_amdgcn_mfma_f32_16x16x32_bf16(a2, b2, acc[n], 0, 0, 0);
    }
#pragma unroll
    for (int n = 0; n < 4; ++n)
#pragma unroll
      for (int r = 0; r < 4; ++r)
        F[hrow + r * 104 + n * 16 + lo] = f2bf(fmaxf(acc[n][r], 0.f));
  }
  // layer 2: K=64 (2 steps), N=64
  {
    f32x4 acc[4];
#pragma unroll
    for (int n = 0; n < 4; ++n) {
      float bb = B2[n * 16 + lo];
      acc[n] = (f32x4){bb, bb, bb, bb};
    }
    s16x8 a0 = *(const s16x8*)(F + arow + 0 + hi * 8);
    s16x8 a1 = *(const s16x8*)(F + arow + 32 + hi * 8);
#pragma unroll
    for (int n = 0; n < 4; ++n) {
      const unsigned short* Bp = &sW2[(n * 16 + lo) * 72 + hi * 8];
      s16x8 b0 = *(const s16x8*)(Bp);
      s16x8 b1 = *(const s16x8*)(Bp + 32);
      acc[n] = __builtin_amdgcn_mfma_f32_16x16x32_bf16(a0, b0, acc[n], 0, 0, 0);
      acc[n] = __builtin_amdgcn_mfma_f32_16x16x32_bf16(a1, b1, acc[n], 0, 0, 0);
    }
#pragma unroll
    for (int n = 0; n < 4; ++n)
#pragma unroll
      for (int r = 0; r < 4; ++r)
        F[hrow + r * 104 + n * 16 + lo] = f2bf(fmaxf(acc[n][r], 0.f));
  }
  // layer 3: K=64 (2 steps), N=128 (8 tiles), fused masked row-max
  float pm[8];
  {
    const int cq = qq2 ? c1 : c0;
    f32x4 acc[8];
#pragma unroll
    for (int n = 0; n < 8; ++n) {
      float bb = B3[n * 16 + lo];
      acc[n] = (f32x4){bb, bb, bb, bb};
    }
    s16x8 a0 = *(const s16x8*)(F + arow + 0 + hi * 8);
    s16x8 a1 = *(const s16x8*)(F + arow + 32 + hi * 8);
#pragma unroll
    for (int n = 0; n < 8; ++n) {
      const unsigned short* Bp = &sW3[(n * 16 + lo) * 72 + hi * 8];
      s16x8 b0 = *(const s16x8*)(Bp);
      s16x8 b1 = *(const s16x8*)(Bp + 32);
      acc[n] = __builtin_amdgcn_mfma_f32_16x16x32_bf16(a0, b0, acc[n], 0, 0, 0);
      acc[n] = __builtin_amdgcn_mfma_f32_16x16x32_bf16(a1, b1, acc[n], 0, 0, 0);
    }
#pragma unroll
    for (int n = 0; n < 8; ++n) {
      float v = -1e30f;
#pragma unroll
      for (int r = 0; r < 4; ++r) {
        int row = 16 * mt + hi * 4 + r;
        if (row < cq) v = fmaxf(v, fmaxf(acc[n][r], 0.f));
      }
      pm[n] = v;
    }
  }
  __syncthreads();  // B5: all sFeat reads done -> reuse as reduction buffer

  float* red = (float*)&sFeat[0][0];  // [2][128][17] floats = 17.4 KB
#pragma unroll
  for (int n = 0; n < 8; ++n)
    red[((qq2 * 128) + n * 16 + lo) * 17 + mt * 4 + hi] = pm[n];
  __syncthreads();  // B6

  if (t < 256) {
    const int gq = t >> 7, cc = t & 127;
    const float* rp = red + (gq * 128 + cc) * 17;
    float v = rp[0];
#pragma unroll
    for (int p = 1; p < 16; ++p) v = fmaxf(v, rp[p]);
    const int qrow = q0 + gq;
    out[(size_t)qrow * 128 + cc] = v;
  }
  if (t == 256 || t == 257) {
    const int gq = t - 256;
    const int qrow = q0 + gq;
    out[524288 + qrow * 3 + 0] = s_ctr[gq][0];
    out[524288 + qrow * 3 + 1] = s_ctr[gq][1];
    out[524288 + qrow * 3 + 2] = s_ctr[gq][2];
    out[536576 + qrow] = (float)g;
  }
}

extern "C" void kernel_launch(void* const* d_in, const int* in_sizes, int n_in,
                              void* d_out, int out_size, void* d_ws, size_t ws_size,
                              hipStream_t stream) {
  const float* x   = (const float*)d_in[0];
  const float* pos = (const float*)d_in[1];
  const float* W1  = (const float*)d_in[3];
  const float* B1  = (const float*)d_in[4];
  const float* W2  = (const float*)d_in[5];
  const float* B2  = (const float*)d_in[6];
  const float* W3  = (const float*)d_in[7];
  const float* B3  = (const float*)d_in[8];
  float* out = (float*)d_out;
  int* idx = (int*)d_ws;  // 4096 ints

  fps_kernel<<<4, 512, 0, stream>>>(pos, idx);
  radconv_kernel<<<2048, 512, 0, stream>>>(x, pos, idx, W1, B1, W2, B2, W3, B3, out);
}